// Round 3
// baseline (1042.945 us; speedup 1.0000x reference)
//
#include <hip/hip_runtime.h>
#include <stdint.h>

#define BB 8
#define NN 256
#define TT 128
#define DD 256
#define HH 8
#define HD 32
#define KTOP 32

typedef short bf16x8 __attribute__((ext_vector_type(8)));
typedef float f32x4 __attribute__((ext_vector_type(4)));

static __device__ __forceinline__ short f2bf(float f) {
  uint32_t u = __float_as_uint(f);
  u += 0x7FFFu + ((u >> 16) & 1u);
  return (short)(u >> 16);
}

static __device__ __forceinline__ uint32_t skey(float f) {
  uint32_t u = __float_as_uint(f);
  return (u & 0x80000000u) ? ~u : (u | 0x80000000u);
}

static __device__ __forceinline__ f32x4 mfma16(bf16x8 a, bf16x8 b, f32x4 c) {
  return __builtin_amdgcn_mfma_f32_16x16x32_bf16(a, b, c, 0, 0, 0);
}

// ---------------- K0: convert Wv, Wo to bf16 ----------------
__global__ __launch_bounds__(256) void k_cvt(const float* __restrict__ wv,
                                             const float* __restrict__ wo,
                                             short* __restrict__ wvb,
                                             short* __restrict__ wob) {
  int idx = blockIdx.x * 256 + threadIdx.x;
  wvb[idx] = f2bf(wv[idx]);
  wob[idx] = f2bf(wo[idx]);
}

// ---------------- K1: q = z@Wq^T, k = z@Wk^T (f32) ----------------
// block = (b, group of 16 rows). 256 threads; thread o computes 16 rows' col o.
__global__ __launch_bounds__(256) void k_qk(const float* __restrict__ z,
                                            const float* __restrict__ Wq,
                                            const float* __restrict__ Wk,
                                            float* __restrict__ q,
                                            float* __restrict__ kk) {
  int b = blockIdx.x >> 4;
  int i0 = (blockIdx.x & 15) * 16;
  __shared__ float zl[DD][16];  // [kx][r]
  int tid = threadIdx.x;
  for (int r = 0; r < 16; ++r)
    zl[tid][r] = z[(size_t)(b * NN + i0 + r) * DD + tid];
  __syncthreads();
  float aq[16], ak[16];
#pragma unroll
  for (int r = 0; r < 16; ++r) { aq[r] = 0.f; ak[r] = 0.f; }
  int o = tid;
  const float4* zc = reinterpret_cast<const float4*>(&zl[0][0]);
  for (int kx = 0; kx < DD; ++kx) {
    float wq = Wq[(size_t)o * DD + kx];
    float wk = Wk[(size_t)o * DD + kx];
    float zr[16];
    ((float4*)zr)[0] = zc[kx * 4 + 0];
    ((float4*)zr)[1] = zc[kx * 4 + 1];
    ((float4*)zr)[2] = zc[kx * 4 + 2];
    ((float4*)zr)[3] = zc[kx * 4 + 3];
#pragma unroll
    for (int r = 0; r < 16; ++r) {
      aq[r] = fmaf(zr[r], wq, aq[r]);
      ak[r] = fmaf(zr[r], wk, ak[r]);
    }
  }
  for (int r = 0; r < 16; ++r) {
    q[(size_t)(b * NN + i0 + r) * DD + o] = aq[r];
    kk[(size_t)(b * NN + i0 + r) * DD + o] = ak[r];
  }
}

// ---------------- K2: scores, raw softmax, exact top-k, masked softmax ------
// block = (b, i). 4 waves; wave w handles heads 2w, 2w+1.
__global__ __launch_bounds__(256) void k_attn(const float* __restrict__ q,
                                              const float* __restrict__ kmat,
                                              const float* __restrict__ adj,
                                              short* __restrict__ attn,
                                              float* __restrict__ attn_mean,
                                              float* __restrict__ raw_mean) {
  int b = blockIdx.x >> 8;
  int i = blockIdx.x & 255;
  __shared__ float ql[DD];
  __shared__ float bias[NN];
  __shared__ float sc[HH][NN];
  __shared__ float ms[HH], invraw[HH], invs2[HH];
  __shared__ uint32_t thr[HH];
  int tid = threadIdx.x;
  ql[tid] = q[(size_t)(b * NN + i) * DD + tid];
  bias[tid] = logf(fmaxf(adj[(size_t)(b * NN + i) * NN + tid], 1e-12f));
  __syncthreads();
  int wv = tid >> 6, lane = tid & 63;
  const float scale = 0.17677669529663687f;  // 1/sqrt(32)
  for (int hh = 0; hh < 2; ++hh) {
    int h = wv * 2 + hh;
    float sv[4];
#pragma unroll
    for (int c = 0; c < 4; ++c) {
      int j = lane + 64 * c;
      const float4* kp =
          (const float4*)&kmat[(size_t)(b * NN + j) * DD + h * HD];
      float s = 0.f;
#pragma unroll
      for (int d4 = 0; d4 < 8; ++d4) {
        float4 kv = kp[d4];
        s = fmaf(ql[h * HD + d4 * 4 + 0], kv.x, s);
        s = fmaf(ql[h * HD + d4 * 4 + 1], kv.y, s);
        s = fmaf(ql[h * HD + d4 * 4 + 2], kv.z, s);
        s = fmaf(ql[h * HD + d4 * 4 + 3], kv.w, s);
      }
      sv[c] = s * scale + bias[j];
      sc[h][j] = sv[c];
    }
    float m = fmaxf(fmaxf(sv[0], sv[1]), fmaxf(sv[2], sv[3]));
    for (int off = 32; off > 0; off >>= 1) m = fmaxf(m, __shfl_xor(m, off, 64));
    float e = expf(sv[0] - m) + expf(sv[1] - m) + expf(sv[2] - m) +
              expf(sv[3] - m);
    for (int off = 32; off > 0; off >>= 1) e += __shfl_xor(e, off, 64);
    // exact 32nd-largest via binary search on sortable keys
    uint32_t kb[4];
#pragma unroll
    for (int c = 0; c < 4; ++c) kb[c] = skey(sv[c]);
    uint32_t lo = 0u, hi = 0xFFFFFFFFu;
    for (int it = 0; it < 32; ++it) {
      uint32_t mid = (uint32_t)(((uint64_t)lo + (uint64_t)hi + 1ull) >> 1);
      int cnt = 0;
#pragma unroll
      for (int c = 0; c < 4; ++c)
        cnt += __popcll(__ballot(kb[c] >= mid));
      if (cnt >= KTOP) lo = mid; else hi = mid - 1u;
    }
    float e2 = 0.f;
#pragma unroll
    for (int c = 0; c < 4; ++c)
      e2 += (kb[c] >= lo) ? expf(sv[c] - m) : 0.f;
    for (int off = 32; off > 0; off >>= 1) e2 += __shfl_xor(e2, off, 64);
    if (lane == 0) {
      ms[h] = m; invraw[h] = 1.f / e; invs2[h] = 1.f / e2; thr[h] = lo;
    }
  }
  __syncthreads();
  int j = tid;
  float rm = 0.f, am = 0.f;
#pragma unroll
  for (int h = 0; h < HH; ++h) {
    float s = sc[h][j];
    float e = expf(s - ms[h]);
    rm += e * invraw[h];
    float a = (skey(s) >= thr[h]) ? e * invs2[h] : 0.f;
    am += a;
    attn[((size_t)(b * HH + h) * NN + i) * NN + j] = f2bf(a);
  }
  raw_mean[(size_t)(b * NN + i) * NN + j] = rm * 0.125f;
  attn_mean[(size_t)(b * NN + i) * NN + j] = am * 0.125f;
}

// ---------------- K3a: v = h_val@Wv^T, stored [b][h][t][d'][j] -------------
// v2 (k_out-v2 recipe): block = (b, o-half, j-half, t-group of 8). The Wv
// o-half (128 rows x 256 cols bf16 = 64 KB) is staged into LDS ONCE,
// XOR-swizzled ((row&7)<<4 on 16B granules) -> conflict-free ds_read_b128.
// One barrier per block (vs 16). 512 blocks = 2/CU, all co-resident.
// Wave w owns j = jhalf*128 + w*32 .. +32 (2 n-tiles) -> each 64B output
// line is wholly owned by one wave (drift-safe). h_val loads are
// 2-kc-deep software-pipelined in registers; next-t kc0/kc1 issued under
// the current t's tail MFMAs + epilogue.
__global__ __launch_bounds__(256, 2) void k_vproj(const float* __restrict__ hv,
                                                  const short* __restrict__ wvb,
                                                  short* __restrict__ vws) {
  __shared__ short wl[128 * 256];  // 64 KB
  int bid = blockIdx.x;
  int b = bid & 7;
  int half_o = (bid >> 3) & 1;  // twins differ by +8 -> same XCD, shared L2
  int half_j = (bid >> 4) & 1;
  int tg = bid >> 5;  // 0..15
  int t0 = tg * 8;
  int tid = threadIdx.x, wv = tid >> 6, lane = tid & 63;
  int lrow = lane & 15, quad = lane >> 4;
  int j0 = half_j * 128 + wv * 32;

  // h_val row pointers for this wave's two n-tiles at t0
  const float* p0 = &hv[((size_t)(b * NN + j0 + lrow) * TT + t0) * DD];
  const float* p1 = &hv[((size_t)(b * NN + j0 + 16 + lrow) * TT + t0) * DD];

  // 2-deep kc pipeline registers (stage = kc&1)
  float4 st[2][4];
  // preload (t0, kc=0) and (t0, kc=1) — latency hides under Wv staging
  st[0][0] = *(const float4*)(p0 + 0 * 32 + quad * 8);
  st[0][1] = *(const float4*)(p0 + 0 * 32 + quad * 8 + 4);
  st[0][2] = *(const float4*)(p1 + 0 * 32 + quad * 8);
  st[0][3] = *(const float4*)(p1 + 0 * 32 + quad * 8 + 4);
  st[1][0] = *(const float4*)(p0 + 1 * 32 + quad * 8);
  st[1][1] = *(const float4*)(p0 + 1 * 32 + quad * 8 + 4);
  st[1][2] = *(const float4*)(p1 + 1 * 32 + quad * 8);
  st[1][3] = *(const float4*)(p1 + 1 * 32 + quad * 8 + 4);

  // stage Wv o-half, swizzled: thread t copies 256 B of row (t>>1)
  {
    int row = tid >> 1, seg = tid & 1;
    const int4* src =
        (const int4*)&wvb[(size_t)(half_o * 128 + row) * DD + seg * 128];
#pragma unroll
    for (int g = 0; g < 16; ++g) {
      int gg = seg * 16 + g;
      int dstb = row * 512 + ((gg * 16) ^ ((row & 7) << 4));
      *(int4*)((char*)wl + dstb) = src[g];
    }
  }
  __syncthreads();

  for (int tt = 0; tt < 8; ++tt) {
    int t = t0 + tt;
    // next-t pointers (clamped in-bounds; tt==7 prefetch is discarded)
    const float* p0n = (tt == 7) ? p0 : p0 + DD;
    const float* p1n = (tt == 7) ? p1 : p1 + DD;
    f32x4 acc[2][8];
#pragma unroll
    for (int nt = 0; nt < 2; ++nt)
#pragma unroll
      for (int mt = 0; mt < 8; ++mt) acc[nt][mt] = (f32x4){0.f, 0.f, 0.f, 0.f};
#pragma unroll
    for (int kc = 0; kc < 8; ++kc) {
      const int cur = kc & 1;
      // convert current stage to bf16 fragments
      bf16x8 bf0, bf1;
      bf0[0] = f2bf(st[cur][0].x); bf0[1] = f2bf(st[cur][0].y);
      bf0[2] = f2bf(st[cur][0].z); bf0[3] = f2bf(st[cur][0].w);
      bf0[4] = f2bf(st[cur][1].x); bf0[5] = f2bf(st[cur][1].y);
      bf0[6] = f2bf(st[cur][1].z); bf0[7] = f2bf(st[cur][1].w);
      bf1[0] = f2bf(st[cur][2].x); bf1[1] = f2bf(st[cur][2].y);
      bf1[2] = f2bf(st[cur][2].z); bf1[3] = f2bf(st[cur][2].w);
      bf1[4] = f2bf(st[cur][3].x); bf1[5] = f2bf(st[cur][3].y);
      bf1[6] = f2bf(st[cur][3].z); bf1[7] = f2bf(st[cur][3].w);
      // issue the +2 prefetch into the freed stage
      if (kc < 6) {
        st[cur][0] = *(const float4*)(p0 + (kc + 2) * 32 + quad * 8);
        st[cur][1] = *(const float4*)(p0 + (kc + 2) * 32 + quad * 8 + 4);
        st[cur][2] = *(const float4*)(p1 + (kc + 2) * 32 + quad * 8);
        st[cur][3] = *(const float4*)(p1 + (kc + 2) * 32 + quad * 8 + 4);
      } else {
        st[cur][0] = *(const float4*)(p0n + (kc - 6) * 32 + quad * 8);
        st[cur][1] = *(const float4*)(p0n + (kc - 6) * 32 + quad * 8 + 4);
        st[cur][2] = *(const float4*)(p1n + (kc - 6) * 32 + quad * 8);
        st[cur][3] = *(const float4*)(p1n + (kc - 6) * 32 + quad * 8 + 4);
      }
#pragma unroll
      for (int mt = 0; mt < 8; ++mt) {
        int brow = mt * 16 + lrow;
        int boff = brow * 512 + ((kc * 64 + quad * 16) ^ ((brow & 7) << 4));
        bf16x8 af = *(const bf16x8*)((const char*)wl + boff);
        acc[0][mt] = mfma16(af, bf0, acc[0][mt]);
        acc[1][mt] = mfma16(af, bf1, acc[1][mt]);
      }
    }
    // epilogue: scalar bf16 stores; nt0/nt1 back-to-back fill each 64B line
#pragma unroll
    for (int mt = 0; mt < 8; ++mt)
#pragma unroll
      for (int r = 0; r < 4; ++r) {
        int o = half_o * 128 + mt * 16 + quad * 4 + r;
        int h = o >> 5, dp = o & 31;
        size_t base = (((size_t)(b * HH + h) * TT + t) * HD + dp) * NN + j0;
        vws[base + lrow] = f2bf(acc[0][mt][r]);
        vws[base + 16 + lrow] = f2bf(acc[1][mt][r]);
      }
    p0 = p0n;
    p1 = p1n;
  }
}

// ---------------- K3b: mixed = attn @ v  (per b,h) -------------------------
// block = (bh, i-tile of 128, col-tile of 256 over (t,d')). wave w: m-tiles
// 2w,2w+1 (A attn from global), B (v) staged in LDS per 32-j chunk.
__global__ __launch_bounds__(256) void k_mix(const short* __restrict__ attn,
                                             const short* __restrict__ vws,
                                             short* __restrict__ mixed) {
  int bid = blockIdx.x;
  int ct = bid & 15;
  int it = (bid >> 4) & 1;
  int bh = bid >> 5;
  int b = bh >> 3, h = bh & 7;
  int i0 = it * 128, c0 = ct * 256;
  __shared__ short vl[256 * 40];
  int tid = threadIdx.x, wv = tid >> 6, lane = tid & 63;
  int lrow = lane & 15, quad = lane >> 4;
  f32x4 acc[2][16];
#pragma unroll
  for (int mi = 0; mi < 2; ++mi)
#pragma unroll
    for (int nt = 0; nt < 16; ++nt) acc[mi][nt] = (f32x4){0.f, 0.f, 0.f, 0.f};
  const short* abase = &attn[((size_t)bh * NN + i0) * NN];
  const short* vbase = &vws[(size_t)bh * 4096 * NN + (size_t)c0 * NN];
  for (int kc = 0; kc < 8; ++kc) {
    __syncthreads();
    {
      const int4* src = (const int4*)&vbase[(size_t)tid * NN + kc * 32];
      int4* dst = (int4*)&vl[tid * 40];
      dst[0] = src[0]; dst[1] = src[1]; dst[2] = src[2]; dst[3] = src[3];
    }
    __syncthreads();
    bf16x8 afrag[2];
#pragma unroll
    for (int mi = 0; mi < 2; ++mi)
      afrag[mi] = *(const bf16x8*)&abase[(size_t)((wv * 2 + mi) * 16 + lrow) *
                                             NN + kc * 32 + quad * 8];
#pragma unroll
    for (int nt = 0; nt < 16; ++nt) {
      bf16x8 bfrag = *(const bf16x8*)&vl[(nt * 16 + lrow) * 40 + quad * 8];
      acc[0][nt] = mfma16(afrag[0], bfrag, acc[0][nt]);
      acc[1][nt] = mfma16(afrag[1], bfrag, acc[1][nt]);
    }
  }
#pragma unroll
  for (int mi = 0; mi < 2; ++mi)
#pragma unroll
    for (int nt = 0; nt < 16; ++nt)
#pragma unroll
      for (int r = 0; r < 4; ++r) {
        int i = i0 + (wv * 2 + mi) * 16 + quad * 4 + r;
        int col = c0 + nt * 16 + lrow;
        int t = col >> 5, dp = col & 31;
        mixed[((size_t)(b * NN + i) * TT + t) * DD + h * HD + dp] =
            f2bf(acc[mi][nt][r]);
      }
}

// ---------------- K4: out = h_val + mixed @ Wo^T ---------------------------
// v2: block = 128 consecutive rows x one 128-col half of Wo. The Wo half
// (64 KB) is staged into LDS ONCE (XOR-swizzled 16B granules -> conflict-free
// ds_read_b128), so the main loop has no staging barriers (2 barriers total
// vs 16 in the old 8-stage version). All 16 A-fragments live in VGPRs.
// A __syncthreads() BEFORE the epilogue re-converges the 4 waves so the
// column-walking hv-load/out-store sweep stays phase-locked (round-1 showed
// drifted epilogues thrash L2 line-merging: FETCH 200MB -> 1GB).
// blockIdx = rowBlock*2 + half so both halves of the same rows co-dispatch.
__global__ __launch_bounds__(256, 2) void k_out(const short* __restrict__ mixed,
                                                const short* __restrict__ wob,
                                                const float* __restrict__ hv,
                                                float* __restrict__ out) {
  __shared__ short wl[128 * 256];  // 64 KB -> 2 blocks/CU
  int tid = threadIdx.x;
  int half = blockIdx.x & 1;
  size_t row0 = (size_t)(blockIdx.x >> 1) * 128;
  int wv = tid >> 6, lane = tid & 63;
  int lrow = lane & 15, quad = lane >> 4;

  // A-fragments up-front: wave wv owns rows [row0+wv*32, +32) = 2 m-tiles.
  bf16x8 afrag[2][8];
  {
    const short* a0 = &mixed[(row0 + wv * 32 + lrow) * DD];
    const short* a1 = &mixed[(row0 + wv * 32 + 16 + lrow) * DD];
#pragma unroll
    for (int kc = 0; kc < 8; ++kc) {
      afrag[0][kc] = *(const bf16x8*)&a0[kc * 32 + quad * 8];
      afrag[1][kc] = *(const bf16x8*)&a1[kc * 32 + quad * 8];
    }
  }
  // Stage Wo rows [half*128, +128): thread t copies 256 B (16 granules of
  // 16 B), granule gg XOR-swizzled by (row&7) within the 512 B row.
  {
    int row = tid >> 1, seg = tid & 1;
    const int4* src =
        (const int4*)&wob[(size_t)(half * 128 + row) * DD + seg * 128];
#pragma unroll
    for (int g = 0; g < 16; ++g) {
      int gg = seg * 16 + g;
      int dstb = row * 512 + ((gg * 16) ^ ((row & 7) << 4));
      *(int4*)((char*)wl + dstb) = src[g];
    }
  }
  __syncthreads();

  f32x4 acc[2][8];
#pragma unroll
  for (int mi = 0; mi < 2; ++mi)
#pragma unroll
    for (int nt = 0; nt < 8; ++nt) acc[mi][nt] = (f32x4){0.f, 0.f, 0.f, 0.f};
#pragma unroll
  for (int kc = 0; kc < 8; ++kc) {
#pragma unroll
    for (int nt = 0; nt < 8; ++nt) {
      int brow = nt * 16 + lrow;
      int boff = brow * 512 + ((kc * 64 + quad * 16) ^ ((brow & 7) << 4));
      bf16x8 bfrag = *(const bf16x8*)((const char*)wl + boff);
      acc[0][nt] = mfma16(afrag[0][kc], bfrag, acc[0][nt]);
      acc[1][nt] = mfma16(afrag[1][kc], bfrag, acc[1][nt]);
    }
  }
  __syncthreads();  // re-converge waves: epilogue sweeps in lockstep

#pragma unroll
  for (int mi = 0; mi < 2; ++mi)
#pragma unroll
    for (int r = 0; r < 4; ++r) {
      size_t row = row0 + wv * 32 + mi * 16 + quad * 4 + r;
#pragma unroll
      for (int nt = 0; nt < 8; ++nt) {
        int o = half * 128 + nt * 16 + lrow;
        out[row * DD + o] = acc[mi][nt][r] + hv[row * DD + o];
      }
    }
}

extern "C" void kernel_launch(void* const* d_in, const int* in_sizes, int n_in,
                              void* d_out, int out_size, void* d_ws,
                              size_t ws_size, hipStream_t stream) {
  (void)in_sizes; (void)n_in; (void)out_size; (void)ws_size;
  const float* hv  = (const float*)d_in[0];
  const float* z   = (const float*)d_in[1];
  const float* adj = (const float*)d_in[2];
  const float* Wq  = (const float*)d_in[3];
  const float* Wk  = (const float*)d_in[4];
  const float* Wv  = (const float*)d_in[5];
  const float* Wo  = (const float*)d_in[6];
  float* out = (float*)d_out;
  float* attn_mean = out + (size_t)BB * NN * TT * DD;
  float* raw_mean = attn_mean + (size_t)BB * NN * NN;

  char* ws = (char*)d_ws;
  float* q = (float*)ws;      ws += (size_t)BB * NN * DD * 4;
  float* k = (float*)ws;      ws += (size_t)BB * NN * DD * 4;
  short* wvb = (short*)ws;    ws += (size_t)DD * DD * 2;
  short* wob = (short*)ws;    ws += (size_t)DD * DD * 2;
  short* attn = (short*)ws;   ws += (size_t)BB * HH * NN * NN * 2;
  short* vws = (short*)ws;    ws += (size_t)BB * HH * TT * HD * NN * 2;
  short* mixed = (short*)ws;  ws += (size_t)BB * NN * TT * DD * 2;

  hipLaunchKernelGGL(k_cvt, dim3(DD * DD / 256), dim3(256), 0, stream,
                     Wv, Wo, wvb, wob);
  hipLaunchKernelGGL(k_qk, dim3(BB * 16), dim3(256), 0, stream,
                     z, Wq, Wk, q, k);
  hipLaunchKernelGGL(k_attn, dim3(BB * NN), dim3(256), 0, stream,
                     q, k, adj, attn, attn_mean, raw_mean);
  hipLaunchKernelGGL(k_vproj, dim3(512), dim3(256), 0, stream,
                     hv, wvb, vws);
  hipLaunchKernelGGL(k_mix, dim3(BB * HH * 2 * 16), dim3(256), 0, stream,
                     attn, vws, mixed);
  hipLaunchKernelGGL(k_out, dim3((BB * NN * TT / 128) * 2), dim3(256), 0,
                     stream, mixed, wob, hv, out);
}

// Round 4
// 891.547 us; speedup vs baseline: 1.1698x; 1.1698x over previous
//
#include <hip/hip_runtime.h>
#include <stdint.h>

#define BB 8
#define NN 256
#define TT 128
#define DD 256
#define HH 8
#define HD 32
#define KTOP 32

typedef short bf16x8 __attribute__((ext_vector_type(8)));
typedef float f32x4 __attribute__((ext_vector_type(4)));

static __device__ __forceinline__ short f2bf(float f) {
  uint32_t u = __float_as_uint(f);
  u += 0x7FFFu + ((u >> 16) & 1u);
  return (short)(u >> 16);
}

static __device__ __forceinline__ uint32_t skey(float f) {
  uint32_t u = __float_as_uint(f);
  return (u & 0x80000000u) ? ~u : (u | 0x80000000u);
}

static __device__ __forceinline__ f32x4 mfma16(bf16x8 a, bf16x8 b, f32x4 c) {
  return __builtin_amdgcn_mfma_f32_16x16x32_bf16(a, b, c, 0, 0, 0);
}

// ---------------- K0: convert Wv, Wo to bf16 ----------------
__global__ __launch_bounds__(256) void k_cvt(const float* __restrict__ wv,
                                             const float* __restrict__ wo,
                                             short* __restrict__ wvb,
                                             short* __restrict__ wob) {
  int idx = blockIdx.x * 256 + threadIdx.x;
  wvb[idx] = f2bf(wv[idx]);
  wob[idx] = f2bf(wo[idx]);
}

// ---------------- K1: q = z@Wq^T, k = z@Wk^T (f32) ----------------
// block = (b, group of 16 rows). 256 threads; thread o computes 16 rows' col o.
__global__ __launch_bounds__(256) void k_qk(const float* __restrict__ z,
                                            const float* __restrict__ Wq,
                                            const float* __restrict__ Wk,
                                            float* __restrict__ q,
                                            float* __restrict__ kk) {
  int b = blockIdx.x >> 4;
  int i0 = (blockIdx.x & 15) * 16;
  __shared__ float zl[DD][16];  // [kx][r]
  int tid = threadIdx.x;
  for (int r = 0; r < 16; ++r)
    zl[tid][r] = z[(size_t)(b * NN + i0 + r) * DD + tid];
  __syncthreads();
  float aq[16], ak[16];
#pragma unroll
  for (int r = 0; r < 16; ++r) { aq[r] = 0.f; ak[r] = 0.f; }
  int o = tid;
  const float4* zc = reinterpret_cast<const float4*>(&zl[0][0]);
  for (int kx = 0; kx < DD; ++kx) {
    float wq = Wq[(size_t)o * DD + kx];
    float wk = Wk[(size_t)o * DD + kx];
    float zr[16];
    ((float4*)zr)[0] = zc[kx * 4 + 0];
    ((float4*)zr)[1] = zc[kx * 4 + 1];
    ((float4*)zr)[2] = zc[kx * 4 + 2];
    ((float4*)zr)[3] = zc[kx * 4 + 3];
#pragma unroll
    for (int r = 0; r < 16; ++r) {
      aq[r] = fmaf(zr[r], wq, aq[r]);
      ak[r] = fmaf(zr[r], wk, ak[r]);
    }
  }
  for (int r = 0; r < 16; ++r) {
    q[(size_t)(b * NN + i0 + r) * DD + o] = aq[r];
    kk[(size_t)(b * NN + i0 + r) * DD + o] = ak[r];
  }
}

// ---------------- K2: scores, raw softmax, exact top-k, masked softmax ------
// block = (b, i). 4 waves; wave w handles heads 2w, 2w+1.
__global__ __launch_bounds__(256) void k_attn(const float* __restrict__ q,
                                              const float* __restrict__ kmat,
                                              const float* __restrict__ adj,
                                              short* __restrict__ attn,
                                              float* __restrict__ attn_mean,
                                              float* __restrict__ raw_mean) {
  int b = blockIdx.x >> 8;
  int i = blockIdx.x & 255;
  __shared__ float ql[DD];
  __shared__ float bias[NN];
  __shared__ float sc[HH][NN];
  __shared__ float ms[HH], invraw[HH], invs2[HH];
  __shared__ uint32_t thr[HH];
  int tid = threadIdx.x;
  ql[tid] = q[(size_t)(b * NN + i) * DD + tid];
  bias[tid] = logf(fmaxf(adj[(size_t)(b * NN + i) * NN + tid], 1e-12f));
  __syncthreads();
  int wv = tid >> 6, lane = tid & 63;
  const float scale = 0.17677669529663687f;  // 1/sqrt(32)
  for (int hh = 0; hh < 2; ++hh) {
    int h = wv * 2 + hh;
    float sv[4];
#pragma unroll
    for (int c = 0; c < 4; ++c) {
      int j = lane + 64 * c;
      const float4* kp =
          (const float4*)&kmat[(size_t)(b * NN + j) * DD + h * HD];
      float s = 0.f;
#pragma unroll
      for (int d4 = 0; d4 < 8; ++d4) {
        float4 kv = kp[d4];
        s = fmaf(ql[h * HD + d4 * 4 + 0], kv.x, s);
        s = fmaf(ql[h * HD + d4 * 4 + 1], kv.y, s);
        s = fmaf(ql[h * HD + d4 * 4 + 2], kv.z, s);
        s = fmaf(ql[h * HD + d4 * 4 + 3], kv.w, s);
      }
      sv[c] = s * scale + bias[j];
      sc[h][j] = sv[c];
    }
    float m = fmaxf(fmaxf(sv[0], sv[1]), fmaxf(sv[2], sv[3]));
    for (int off = 32; off > 0; off >>= 1) m = fmaxf(m, __shfl_xor(m, off, 64));
    float e = expf(sv[0] - m) + expf(sv[1] - m) + expf(sv[2] - m) +
              expf(sv[3] - m);
    for (int off = 32; off > 0; off >>= 1) e += __shfl_xor(e, off, 64);
    // exact 32nd-largest via binary search on sortable keys
    uint32_t kb[4];
#pragma unroll
    for (int c = 0; c < 4; ++c) kb[c] = skey(sv[c]);
    uint32_t lo = 0u, hi = 0xFFFFFFFFu;
    for (int it = 0; it < 32; ++it) {
      uint32_t mid = (uint32_t)(((uint64_t)lo + (uint64_t)hi + 1ull) >> 1);
      int cnt = 0;
#pragma unroll
      for (int c = 0; c < 4; ++c)
        cnt += __popcll(__ballot(kb[c] >= mid));
      if (cnt >= KTOP) lo = mid; else hi = mid - 1u;
    }
    float e2 = 0.f;
#pragma unroll
    for (int c = 0; c < 4; ++c)
      e2 += (kb[c] >= lo) ? expf(sv[c] - m) : 0.f;
    for (int off = 32; off > 0; off >>= 1) e2 += __shfl_xor(e2, off, 64);
    if (lane == 0) {
      ms[h] = m; invraw[h] = 1.f / e; invs2[h] = 1.f / e2; thr[h] = lo;
    }
  }
  __syncthreads();
  int j = tid;
  float rm = 0.f, am = 0.f;
#pragma unroll
  for (int h = 0; h < HH; ++h) {
    float s = sc[h][j];
    float e = expf(s - ms[h]);
    rm += e * invraw[h];
    float a = (skey(s) >= thr[h]) ? e * invs2[h] : 0.f;
    am += a;
    attn[((size_t)(b * HH + h) * NN + i) * NN + j] = f2bf(a);
  }
  raw_mean[(size_t)(b * NN + i) * NN + j] = rm * 0.125f;
  attn_mean[(size_t)(b * NN + i) * NN + j] = am * 0.125f;
}

// ---------------- K3a: v = h_val@Wv^T, stored [b][h][t][d'][j] -------------
// Round-2 known-good version (172 us). A-operand = Wv (m=o), B-operand =
// h_val rows (n=j) so C cols = j (fast dim). block = (b, t, j-group of 64).
// wave w owns n-tile w (16 j), all 16 m-tiles. hv read exactly once per
// element; per-wave 32 B j-chunks keep write lines clean. (Round-3 barrier-
// free rewrite regressed: duplicated hv reads missed L2, FETCH 132->395 MB.)
__global__ __launch_bounds__(256) void k_vproj(const float* __restrict__ hv,
                                               const short* __restrict__ wvb,
                                               short* __restrict__ vws) {
  int bid = blockIdx.x;
  int jb = bid & 3;
  int t = (bid >> 2) & (TT - 1);
  int b = bid >> 9;
  int j0 = jb * 64;
  __shared__ short wl[256 * 40];
  int tid = threadIdx.x, wv = tid >> 6, lane = tid & 63;
  int lrow = lane & 15, quad = lane >> 4;
  f32x4 acc[16];
#pragma unroll
  for (int m = 0; m < 16; ++m) acc[m] = (f32x4){0.f, 0.f, 0.f, 0.f};
  int j = j0 + wv * 16 + lrow;
  const float* hrow = &hv[((size_t)(b * NN + j) * TT + t) * DD];
  for (int kc = 0; kc < 8; ++kc) {
    __syncthreads();
    {
      const int4* src = (const int4*)&wvb[(size_t)tid * DD + kc * 32];
      int4* dst = (int4*)&wl[tid * 40];
      dst[0] = src[0]; dst[1] = src[1]; dst[2] = src[2]; dst[3] = src[3];
    }
    __syncthreads();
    const float4* hp = (const float4*)&hrow[kc * 32 + quad * 8];
    float4 f0 = hp[0], f1 = hp[1];
    bf16x8 bfrag;
    bfrag[0] = f2bf(f0.x); bfrag[1] = f2bf(f0.y);
    bfrag[2] = f2bf(f0.z); bfrag[3] = f2bf(f0.w);
    bfrag[4] = f2bf(f1.x); bfrag[5] = f2bf(f1.y);
    bfrag[6] = f2bf(f1.z); bfrag[7] = f2bf(f1.w);
#pragma unroll
    for (int mt = 0; mt < 16; ++mt) {
      const bf16x8* ap = (const bf16x8*)&wl[(mt * 16 + lrow) * 40 + quad * 8];
      acc[mt] = mfma16(*ap, bfrag, acc[mt]);
    }
  }
#pragma unroll
  for (int mt = 0; mt < 16; ++mt) {
#pragma unroll
    for (int r = 0; r < 4; ++r) {
      int o = mt * 16 + quad * 4 + r;
      int h = o >> 5, dp = o & 31;
      vws[(((size_t)(b * HH + h) * TT + t) * HD + dp) * NN + j] =
          f2bf(acc[mt][r]);
    }
  }
}

// ---------------- K3b: mixed = attn @ v  (per b,h) -------------------------
// v2 (k_out-v2 clone): block = (bh, i-block of 128, col-block of 128).
// B = vws cols [c0, c0+128) x 256 j = 64 KB staged into LDS ONCE,
// XOR-swizzled ((row&7)<<4 on 16B granules) -> conflict-free ds_read_b128.
// 2 barriers per block (vs 16). A (attn) fragments live in VGPRs
// (2 m-tiles/wave x 8 kc). col-block is the INNERMOST bid digit so all 32
// consumers of one 64 KB attn panel are co-resident -> attn re-reads are
// L2/L3 hits (attn = 134 MB, just written, L3-resident); vws and mixed
// each touched exactly once. Pre-epilogue sync keeps store sweep lockstep.
__global__ __launch_bounds__(256, 2) void k_mix(const short* __restrict__ attn,
                                                const short* __restrict__ vws,
                                                short* __restrict__ mixed) {
  __shared__ short wl[128 * 256];  // 64 KB -> 2 blocks/CU
  int bid = blockIdx.x;
  int cb = bid & 31;         // col-block (128 cols), innermost
  int ib = (bid >> 5) & 1;   // i-block (128 rows)
  int bh = bid >> 6;
  int b = bh >> 3, h = bh & 7;
  int c0 = cb * 128, i0 = ib * 128;
  int tid = threadIdx.x, wv = tid >> 6, lane = tid & 63;
  int lrow = lane & 15, quad = lane >> 4;

  // A-fragments up-front: wave wv owns i rows [i0+wv*32, +32) = 2 m-tiles.
  bf16x8 afrag[2][8];
  {
    const short* a0 = &attn[((size_t)bh * NN + i0 + wv * 32 + lrow) * NN];
    const short* a1 = a0 + 16 * NN;
#pragma unroll
    for (int kc = 0; kc < 8; ++kc) {
      afrag[0][kc] = *(const bf16x8*)&a0[kc * 32 + quad * 8];
      afrag[1][kc] = *(const bf16x8*)&a1[kc * 32 + quad * 8];
    }
  }
  // Stage B: vws rows (= cols of V) c0..c0+127, each 256 j = 512 B,
  // thread t copies 256 B of row (t>>1), 16B granules XOR-swizzled.
  {
    int row = tid >> 1, seg = tid & 1;
    const int4* src =
        (const int4*)&vws[((size_t)bh * 4096 + c0 + row) * NN + seg * 128];
#pragma unroll
    for (int g = 0; g < 16; ++g) {
      int gg = seg * 16 + g;
      int dstb = row * 512 + ((gg * 16) ^ ((row & 7) << 4));
      *(int4*)((char*)wl + dstb) = src[g];
    }
  }
  __syncthreads();

  f32x4 acc[2][8];
#pragma unroll
  for (int mi = 0; mi < 2; ++mi)
#pragma unroll
    for (int nt = 0; nt < 8; ++nt) acc[mi][nt] = (f32x4){0.f, 0.f, 0.f, 0.f};
#pragma unroll
  for (int kc = 0; kc < 8; ++kc) {
#pragma unroll
    for (int nt = 0; nt < 8; ++nt) {
      int brow = nt * 16 + lrow;
      int boff = brow * 512 + ((kc * 64 + quad * 16) ^ ((brow & 7) << 4));
      bf16x8 bfrag = *(const bf16x8*)((const char*)wl + boff);
      acc[0][nt] = mfma16(afrag[0][kc], bfrag, acc[0][nt]);
      acc[1][nt] = mfma16(afrag[1][kc], bfrag, acc[1][nt]);
    }
  }
  __syncthreads();  // re-converge waves: epilogue sweeps in lockstep

#pragma unroll
  for (int mi = 0; mi < 2; ++mi)
#pragma unroll
    for (int nt = 0; nt < 8; ++nt)
#pragma unroll
      for (int r = 0; r < 4; ++r) {
        int i = i0 + wv * 32 + mi * 16 + quad * 4 + r;
        int col = c0 + nt * 16 + lrow;
        int t = col >> 5, dp = col & 31;
        mixed[((size_t)(b * NN + i) * TT + t) * DD + h * HD + dp] =
            f2bf(acc[mi][nt][r]);
      }
}

// ---------------- K4: out = h_val + mixed @ Wo^T ---------------------------
// v2: block = 128 consecutive rows x one 128-col half of Wo. The Wo half
// (64 KB) is staged into LDS ONCE (XOR-swizzled 16B granules -> conflict-free
// ds_read_b128), so the main loop has no staging barriers (2 barriers total
// vs 16 in the old 8-stage version). All 16 A-fragments live in VGPRs.
// A __syncthreads() BEFORE the epilogue re-converges the 4 waves so the
// column-walking hv-load/out-store sweep stays phase-locked (round-1 showed
// drifted epilogues thrash L2 line-merging: FETCH 200MB -> 1GB).
// blockIdx = rowBlock*2 + half so both halves of the same rows co-dispatch.
__global__ __launch_bounds__(256, 2) void k_out(const short* __restrict__ mixed,
                                                const short* __restrict__ wob,
                                                const float* __restrict__ hv,
                                                float* __restrict__ out) {
  __shared__ short wl[128 * 256];  // 64 KB -> 2 blocks/CU
  int tid = threadIdx.x;
  int half = blockIdx.x & 1;
  size_t row0 = (size_t)(blockIdx.x >> 1) * 128;
  int wv = tid >> 6, lane = tid & 63;
  int lrow = lane & 15, quad = lane >> 4;

  // A-fragments up-front: wave wv owns rows [row0+wv*32, +32) = 2 m-tiles.
  bf16x8 afrag[2][8];
  {
    const short* a0 = &mixed[(row0 + wv * 32 + lrow) * DD];
    const short* a1 = &mixed[(row0 + wv * 32 + 16 + lrow) * DD];
#pragma unroll
    for (int kc = 0; kc < 8; ++kc) {
      afrag[0][kc] = *(const bf16x8*)&a0[kc * 32 + quad * 8];
      afrag[1][kc] = *(const bf16x8*)&a1[kc * 32 + quad * 8];
    }
  }
  // Stage Wo rows [half*128, +128): thread t copies 256 B (16 granules of
  // 16 B), granule gg XOR-swizzled by (row&7) within the 512 B row.
  {
    int row = tid >> 1, seg = tid & 1;
    const int4* src =
        (const int4*)&wob[(size_t)(half * 128 + row) * DD + seg * 128];
#pragma unroll
    for (int g = 0; g < 16; ++g) {
      int gg = seg * 16 + g;
      int dstb = row * 512 + ((gg * 16) ^ ((row & 7) << 4));
      *(int4*)((char*)wl + dstb) = src[g];
    }
  }
  __syncthreads();

  f32x4 acc[2][8];
#pragma unroll
  for (int mi = 0; mi < 2; ++mi)
#pragma unroll
    for (int nt = 0; nt < 8; ++nt) acc[mi][nt] = (f32x4){0.f, 0.f, 0.f, 0.f};
#pragma unroll
  for (int kc = 0; kc < 8; ++kc) {
#pragma unroll
    for (int nt = 0; nt < 8; ++nt) {
      int brow = nt * 16 + lrow;
      int boff = brow * 512 + ((kc * 64 + quad * 16) ^ ((brow & 7) << 4));
      bf16x8 bfrag = *(const bf16x8*)((const char*)wl + boff);
      acc[0][nt] = mfma16(afrag[0][kc], bfrag, acc[0][nt]);
      acc[1][nt] = mfma16(afrag[1][kc], bfrag, acc[1][nt]);
    }
  }
  __syncthreads();  // re-converge waves: epilogue sweeps in lockstep

#pragma unroll
  for (int mi = 0; mi < 2; ++mi)
#pragma unroll
    for (int r = 0; r < 4; ++r) {
      size_t row = row0 + wv * 32 + mi * 16 + quad * 4 + r;
#pragma unroll
      for (int nt = 0; nt < 8; ++nt) {
        int o = half * 128 + nt * 16 + lrow;
        out[row * DD + o] = acc[mi][nt][r] + hv[row * DD + o];
      }
    }
}

extern "C" void kernel_launch(void* const* d_in, const int* in_sizes, int n_in,
                              void* d_out, int out_size, void* d_ws,
                              size_t ws_size, hipStream_t stream) {
  (void)in_sizes; (void)n_in; (void)out_size; (void)ws_size;
  const float* hv  = (const float*)d_in[0];
  const float* z   = (const float*)d_in[1];
  const float* adj = (const float*)d_in[2];
  const float* Wq  = (const float*)d_in[3];
  const float* Wk  = (const float*)d_in[4];
  const float* Wv  = (const float*)d_in[5];
  const float* Wo  = (const float*)d_in[6];
  float* out = (float*)d_out;
  float* attn_mean = out + (size_t)BB * NN * TT * DD;
  float* raw_mean = attn_mean + (size_t)BB * NN * NN;

  char* ws = (char*)d_ws;
  float* q = (float*)ws;      ws += (size_t)BB * NN * DD * 4;
  float* k = (float*)ws;      ws += (size_t)BB * NN * DD * 4;
  short* wvb = (short*)ws;    ws += (size_t)DD * DD * 2;
  short* wob = (short*)ws;    ws += (size_t)DD * DD * 2;
  short* attn = (short*)ws;   ws += (size_t)BB * HH * NN * NN * 2;
  short* vws = (short*)ws;    ws += (size_t)BB * HH * TT * HD * NN * 2;
  short* mixed = (short*)ws;  ws += (size_t)BB * NN * TT * DD * 2;

  hipLaunchKernelGGL(k_cvt, dim3(DD * DD / 256), dim3(256), 0, stream,
                     Wv, Wo, wvb, wob);
  hipLaunchKernelGGL(k_qk, dim3(BB * 16), dim3(256), 0, stream,
                     z, Wq, Wk, q, k);
  hipLaunchKernelGGL(k_attn, dim3(BB * NN), dim3(256), 0, stream,
                     q, k, adj, attn, attn_mean, raw_mean);
  hipLaunchKernelGGL(k_vproj, dim3(BB * TT * 4), dim3(256), 0, stream,
                     hv, wvb, vws);
  hipLaunchKernelGGL(k_mix, dim3(64 * 2 * 32), dim3(256), 0, stream,
                     attn, vws, mixed);
  hipLaunchKernelGGL(k_out, dim3((BB * NN * TT / 128) * 2), dim3(256), 0,
                     stream, mixed, wob, hv, out);
}